// Round 8
// baseline (330.724 us; speedup 1.0000x reference)
//
#include <hip/hip_runtime.h>
#include <hip/hip_bf16.h>
#include <cstdint>
#include <cstddef>

// LearnableUpsampler: quant -> convT(K=4,s=2) -> quant -> conv7+silu -> quant -> conv7 + res -> LN
// Round 8: K-split across waves. Block = 4 waves, tile 32M x 128N; wave (nhalf, tgroup):
// tgroup 0 -> taps 0..T0, tgroup 1 -> taps T0..NTAPS (each folds its own tap scales,
// fp32 partials reduced via LDS). 4096 waves = 4/SIMD (2x R6). Barrier-free K-loop,
// B from L2 to VGPRs (depth-4), A from LDS (depth-2).

#define B_ 2
#define T_ 2048
#define L_ 4096
#define C_ 512

static constexpr int NUP = 512 * 512 * 4;
static constexpr int NR  = 512 * 512 * 7;

using v4i  = __attribute__((ext_vector_type(4))) int;
using v16i = __attribute__((ext_vector_type(16))) int;

__device__ __forceinline__ void gl16(const void* g, void* l) {
  __builtin_amdgcn_global_load_lds((const __attribute__((address_space(1))) unsigned int*)g,
                                   (__attribute__((address_space(3))) unsigned int*)l,
                                   16, 0, 0);
}

// ---------------- reductions ----------------

__device__ inline float block_reduce_sum_256(float v) {
  #pragma unroll
  for (int off = 32; off > 0; off >>= 1) v += __shfl_down(v, off, 64);
  __shared__ float s[4];
  __syncthreads();
  if ((threadIdx.x & 63) == 0) s[threadIdx.x >> 6] = v;
  __syncthreads();
  return (s[0] + s[1]) + (s[2] + s[3]);
}

// one launch: blockIdx.y selects tensor {0:w_up,1:w_r1,2:w_r2}
__global__ void abssum3_kernel(const float* __restrict__ w0, const float* __restrict__ w1,
                               const float* __restrict__ w2, float* __restrict__ out) {
  int y = blockIdx.y;
  const float* w = (y == 0) ? w0 : (y == 1) ? w1 : w2;
  int n = (y == 0) ? NUP : NR;
  int idx = blockIdx.x * 256 + threadIdx.x;
  float s = 0.f;
  for (int i = idx; i < n; i += gridDim.x * 256) s += fabsf(w[i]);
  s = block_reduce_sum_256(s);
  if (threadIdx.x == 0) atomicAdd(out + y, s);
}

// ---------------- ternarize + repack, one launch; layout [tap][kq32][co512][16] ----------------
__global__ void tern_all_kernel(const float* __restrict__ wu, const float* __restrict__ w1,
                                const float* __restrict__ w2, int8_t* __restrict__ ou,
                                int8_t* __restrict__ o1, int8_t* __restrict__ o2,
                                const float* __restrict__ wsum) {
  int y = blockIdx.y;
  int idx = blockIdx.x * 256 + threadIdx.x;
  if (y == 0) {
    if (idx >= NUP) return;
    float mean = wsum[0] * (1.0f / (float)NUP);
    float scale = 1.0f / fmaxf(mean, 1e-5f);
    float t = rintf(wu[idx] * scale);
    t = fminf(fmaxf(t, -1.f), 1.f);
    int ci = idx >> 11;
    int co = (idx >> 2) & 511;
    int k = idx & 3;
    // ptap order: parity0 {k=3,k=1}, parity1 {k=2,k=0}
    int ptap = (k == 3) ? 0 : (k == 1) ? 1 : (k == 2) ? 2 : 3;
    ou[(((size_t)ptap * 32 + (ci >> 4)) * 512 + co) * 16 + (ci & 15)] = (int8_t)t;
  } else {
    if (idx >= NR) return;
    const float* w = (y == 1) ? w1 : w2;
    int8_t* o = (y == 1) ? o1 : o2;
    float mean = wsum[y] * (1.0f / (float)NR);
    float scale = 1.0f / fmaxf(mean, 1e-5f);
    float t = rintf(w[idx] * scale);
    t = fminf(fmaxf(t, -1.f), 1.f);
    int co = idx / 3584;
    int rem = idx - co * 3584;
    int ci = rem / 7;
    int k = rem - ci * 7;
    o[(((size_t)k * 32 + (ci >> 4)) * 512 + co) * 16 + (ci & 15)] = (int8_t)t;
  }
}

// ---------------- per-token activation quant; packed q layout [b][kq32][LinH][16] ----------------
__global__ void act_quant_kernel(const float* __restrict__ x, int8_t* __restrict__ qd,
                                 float* __restrict__ inv, int Lb, int lbsh, int LinH) {
  int tok = blockIdx.x;
  int b = tok >> lbsh;
  int t = tok & (Lb - 1);
  const float* row = x + (size_t)tok * C_;
  int tid = threadIdx.x;
  float v0 = row[tid];
  float v1 = row[tid + 256];
  float m = fmaxf(fabsf(v0), fabsf(v1));
  #pragma unroll
  for (int off = 32; off > 0; off >>= 1) m = fmaxf(m, __shfl_down(m, off, 64));
  __shared__ float s[4];
  __shared__ __align__(16) int8_t sq[512];
  if ((tid & 63) == 0) s[tid >> 6] = m;
  __syncthreads();
  m = fmaxf(fmaxf(s[0], s[1]), fmaxf(s[2], s[3]));
  float scale = 127.0f / fmaxf(m, 1e-5f);
  float q0 = fminf(fmaxf(rintf(v0 * scale), -128.f), 127.f);
  float q1 = fminf(fmaxf(rintf(v1 * scale), -128.f), 127.f);
  sq[tid] = (int8_t)q0;
  sq[tid + 256] = (int8_t)q1;
  __syncthreads();
  if (tid < 32)
    *(v4i*)(qd + ((size_t)(b * 32 + tid) * LinH + 8 + t) * 16) = *(const v4i*)(sq + tid * 16);
  if (tid == 0) inv[(size_t)b * LinH + 8 + t] = 1.0f / scale;
}

// ---------------- MFMA conv: tap-split int8 GEMM ----------------
// Block 256 thr (4 waves), tile 32(M) x 128(N). Wave = (nhalf = w&1, tgroup = w>>1).
// tgroup 0: taps [0,T0); tgroup 1: taps [T0,NTAPS). Each wave folds its own tap scales;
// fp32 partials reduced via LDS (sRed) then tgroup-0 waves run the epilogue.
// sA[kq32][row40][16] staged once; 2 barriers total. B loads depth-4, A loads depth-2.
template<int NTAPS, bool CONVT>
__global__ __launch_bounds__(256, 4)
void conv_mfma(const int8_t* __restrict__ qin, const float* __restrict__ invp, int LinH,
               const int8_t* __restrict__ wq, const float* __restrict__ wsum, int widx,
               float wninv, const float* __restrict__ bias, const float* __restrict__ res,
               float* __restrict__ outp, int Lout, int do_silu) {
  constexpr int T0 = (NTAPS + 1) / 2;
  __shared__ __align__(16) int8_t sA[32 * 40 * 16];   // 20480 B
  __shared__ float sRed[2][2][16][64];                // 16384 B
  __shared__ float sInv[40];

  const int tid = threadIdx.x;
  const int w = tid >> 6, lane = tid & 63, q = lane >> 5, l31 = lane & 31;
  const int nhalf = w & 1, tgroup = w >> 1;
  const int n0 = (blockIdx.x & 3) * 128;
  const int t0 = (blockIdx.x >> 2) * 32;
  const int b = blockIdx.y;
  int s0 = -3;
  const int8_t* wq_p = wq;
  float* out_b = outp + (size_t)b * Lout * 512;
  int rstride = 512;
  if (CONVT) {
    int parity = blockIdx.z;
    s0 = parity - 1;
    wq_p += (size_t)parity * 2 * 32 * 512 * 16;
    out_b += parity * 512;
    rstride = 1024;
  }
  const int8_t* qin_b = qin + (size_t)b * 32 * LinH * 16;
  const float* inv_b = invp + (size_t)b * LinH + 8;

  // stage A once: 1280 units of 16B, [kq32][row40][16]; buf row r <-> token t0-4+r
  #pragma unroll
  for (int i = 0; i < 5; ++i) {
    int u = i * 256 + tid;
    int kq = u / 40;
    int row = u - kq * 40;
    gl16(qin_b + ((size_t)kq * LinH + (size_t)(t0 + 4 + row)) * 16,
         sA + (size_t)(i * 256 + w * 64) * 16);
  }
  if (tid < 40) sInv[tid] = inv_b[t0 - 4 + tid];
  __syncthreads();  // barrier 1

  const int tap_lo = tgroup ? T0 : 0;
  const int tap_hi = tgroup ? NTAPS : T0;
  const int ncol = n0 + nhalf * 64;

  float fs0[16], fs1[16];
  #pragma unroll
  for (int r = 0; r < 16; ++r) { fs0[r] = 0.f; fs1[r] = 0.f; }

  // pipeline: A depth-2 (LDS), B depth-4 (global/L2)
  v4i afp[2], b0p[4], b1p[4];
  #pragma unroll
  for (int i = 0; i < 2; ++i) {
    int kq32 = i * 2 + q;
    afp[i] = *(const v4i*)(sA + ((size_t)kq32 * 40 + 4 + s0 + tap_lo + l31) * 16);
  }
  #pragma unroll
  for (int i = 0; i < 4; ++i) {
    int kq32 = i * 2 + q;
    const int8_t* bp = wq_p + (((size_t)(tap_lo * 32 + kq32) * 512) + ncol + l31) * 16;
    b0p[i] = *(const v4i*)bp;
    b1p[i] = *(const v4i*)(bp + 512);
  }

  for (int tap = tap_lo; tap < tap_hi; ++tap) {
    const int shift = s0 + tap;
    v16i acc0{}, acc1{};
    #pragma unroll
    for (int r = 0; r < 16; ++r) { acc0[r] = 0; acc1[r] = 0; }
    #pragma unroll
    for (int ks = 0; ks < 16; ++ks) {
      v4i a_c = afp[ks & 1], b0_c = b0p[ks & 3], b1_c = b1p[ks & 3];
      // A prefetch (target step ks+2)
      if (ks < 14) {
        int kq32 = (ks + 2) * 2 + q;
        afp[ks & 1] = *(const v4i*)(sA + ((size_t)kq32 * 40 + 4 + shift + l31) * 16);
      } else if (tap + 1 < tap_hi) {
        int kq32 = (ks - 14) * 2 + q;
        afp[ks & 1] = *(const v4i*)(sA + ((size_t)kq32 * 40 + 4 + shift + 1 + l31) * 16);
      }
      // B prefetch (target step ks+4)
      if (ks < 12) {
        int kq32 = (ks + 4) * 2 + q;
        const int8_t* bp = wq_p + (((size_t)(tap * 32 + kq32) * 512) + ncol + l31) * 16;
        b0p[ks & 3] = *(const v4i*)bp;
        b1p[ks & 3] = *(const v4i*)(bp + 512);
      } else if (tap + 1 < tap_hi) {
        int kq32 = (ks - 12) * 2 + q;
        const int8_t* bp = wq_p + (((size_t)((tap + 1) * 32 + kq32) * 512) + ncol + l31) * 16;
        b0p[ks & 3] = *(const v4i*)bp;
        b1p[ks & 3] = *(const v4i*)(bp + 512);
      }
      acc0 = __builtin_amdgcn_mfma_i32_32x32x32_i8(a_c, b0_c, acc0, 0, 0, 0);
      acc1 = __builtin_amdgcn_mfma_i32_32x32x32_i8(a_c, b1_c, acc1, 0, 0, 0);
    }
    // fold i32 -> fp32 with per-input-row scale
    #pragma unroll
    for (int r = 0; r < 16; ++r) {
      int ro = (r & 3) + 8 * (r >> 2) + 4 * q;
      float sc = sInv[4 + shift + ro];
      fs0[r] = fmaf((float)acc0[r], sc, fs0[r]);
      fs1[r] = fmaf((float)acc1[r], sc, fs1[r]);
    }
  }

  // cross-wave reduction: tgroup 1 writes partials, tgroup 0 adds + epilogue
  if (tgroup == 1) {
    #pragma unroll
    for (int r = 0; r < 16; ++r) {
      sRed[nhalf][0][r][lane] = fs0[r];
      sRed[nhalf][1][r][lane] = fs1[r];
    }
  }
  __syncthreads();  // barrier 2
  if (tgroup == 0) {
    #pragma unroll
    for (int r = 0; r < 16; ++r) {
      fs0[r] += sRed[nhalf][0][r][lane];
      fs1[r] += sRed[nhalf][1][r][lane];
    }
    float wdq = fmaxf(wsum[widx] * wninv, 1e-5f);
    #pragma unroll
    for (int nt = 0; nt < 2; ++nt) {
      int col = ncol + nt * 32 + l31;
      float bv = bias[col];
      #pragma unroll
      for (int r = 0; r < 16; ++r) {
        int row = t0 + (r & 3) + 8 * (r >> 2) + 4 * q;
        float y = (nt == 0 ? fs0[r] : fs1[r]) * wdq + bv;
        if (do_silu) y = y / (1.0f + expf(-y));
        if (res) y += res[((size_t)b * Lout + row) * 512 + col];
        out_b[(size_t)row * rstride + col] = y;
      }
    }
  }
}

// ---------------- LayerNorm over channels ----------------
__global__ void ln_kernel(const float* __restrict__ x, const float* __restrict__ g,
                          const float* __restrict__ be, float* __restrict__ out) {
  int tok = blockIdx.x;
  const float* row = x + (size_t)tok * C_;
  int tid = threadIdx.x;
  float v0 = row[tid];
  float v1 = row[tid + 256];
  float total = block_reduce_sum_256(v0 + v1);
  float mu = total * (1.0f / (float)C_);
  float d0 = v0 - mu, d1 = v1 - mu;
  float vs = block_reduce_sum_256(d0 * d0 + d1 * d1);
  float var = vs * (1.0f / (float)C_);
  float r = 1.0f / sqrtf(var + 1e-5f);
  size_t base = (size_t)tok * C_;
  out[base + tid] = d0 * r * g[tid] + be[tid];
  out[base + tid + 256] = d1 * r * g[tid + 256] + be[tid + 256];
}

// ---------------- launch ----------------

extern "C" void kernel_launch(void* const* d_in, const int* in_sizes, int n_in,
                              void* d_out, int out_size, void* d_ws, size_t ws_size,
                              hipStream_t stream) {
  const float* x    = (const float*)d_in[0];
  const float* w_up = (const float*)d_in[1];
  const float* b_up = (const float*)d_in[2];
  const float* w_r1 = (const float*)d_in[3];
  const float* b_r1 = (const float*)d_in[4];
  const float* w_r2 = (const float*)d_in[5];
  const float* b_r2 = (const float*)d_in[6];
  const float* ln_w = (const float*)d_in[7];
  const float* ln_b = (const float*)d_in[8];
  float* out = (float*)d_out;

  const int LXH = T_ + 16;   // 2064 rows per batch (halo 8 each side)
  const int LHH = L_ + 16;   // 4112

  char* ws = (char*)d_ws;
  size_t off = 0;
  auto alloc = [&](size_t sz) { size_t p = off; off += (sz + 255) & ~(size_t)255; return p; };
  // wsum, qx, qh contiguous -> one zeroing memset
  float*  wsum = (float*) (ws + alloc(256));
  int8_t* qx   = (int8_t*)(ws + alloc((size_t)B_ * 32 * LXH * 16));   // 2.1 MB
  int8_t* qh   = (int8_t*)(ws + alloc((size_t)B_ * 32 * LHH * 16));   // 4.2 MB
  size_t zero_bytes = off;
  float*  invx = (float*) (ws + alloc((size_t)B_ * LXH * 4));
  float*  invh = (float*) (ws + alloc((size_t)B_ * LHH * 4));
  int8_t* wqup = (int8_t*)(ws + alloc((size_t)4 * 32 * 512 * 16));    // 1 MB
  int8_t* wq1  = (int8_t*)(ws + alloc((size_t)7 * 32 * 512 * 16));    // 1.8 MB
  int8_t* wq2  = (int8_t*)(ws + alloc((size_t)7 * 32 * 512 * 16));    // 1.8 MB
  float*  h    = (float*) (ws + alloc((size_t)B_ * L_ * C_ * 4));     // 16.8 MB
  float*  r    = (float*) (ws + alloc((size_t)B_ * L_ * C_ * 4));     // 16.8 MB

  hipMemsetAsync(ws, 0, zero_bytes, stream);  // wsum + qx + qh (zero halos)

  abssum3_kernel<<<dim3(256, 3), 256, 0, stream>>>(w_up, w_r1, w_r2, wsum);
  tern_all_kernel<<<dim3(NR / 256, 3), 256, 0, stream>>>(w_up, w_r1, w_r2,
                                                         wqup, wq1, wq2, wsum);

  act_quant_kernel<<<B_ * T_, 256, 0, stream>>>(x, qx, invx, T_, 11, LXH);

  // convT: grid (4 ntiles * 64 mtiles, B, parity); block tile 32M x 128N, tap-split 1/1
  conv_mfma<2, true><<<dim3(4 * 64, B_, 2), 256, 0, stream>>>(
      qx, invx, LXH, wqup, wsum, 0, 1.0f / (float)NUP, b_up, nullptr, h, L_, 0);

  act_quant_kernel<<<B_ * L_, 256, 0, stream>>>(h, qh, invh, L_, 12, LHH);

  // conv7: grid (4 ntiles * 128 mtiles, B); tap-split 4/3
  conv_mfma<7, false><<<dim3(4 * 128, B_, 1), 256, 0, stream>>>(
      qh, invh, LHH, wq1, wsum, 1, 1.0f / (float)NR, b_r1, nullptr, r, L_, 1);

  act_quant_kernel<<<B_ * L_, 256, 0, stream>>>(r, qh, invh, L_, 12, LHH);

  conv_mfma<7, false><<<dim3(4 * 128, B_, 1), 256, 0, stream>>>(
      qh, invh, LHH, wq2, wsum, 2, 1.0f / (float)NR, b_r2, h, r, L_, 0);

  ln_kernel<<<B_ * L_, 256, 0, stream>>>(r, ln_w, ln_b, out);
}

// Round 9
// 232.811 us; speedup vs baseline: 1.4206x; 1.4206x over previous
//
#include <hip/hip_runtime.h>
#include <hip/hip_bf16.h>
#include <cstdint>
#include <cstddef>

// LearnableUpsampler: quant -> convT(K=4,s=2) -> quant -> conv7+silu -> quant -> conv7 + res -> LN
// Round 9: wave tile 32x32 (1 acc) -> 4096 waves = 4/SIMD resident WITHOUT launch_bounds
// register coercion (R8's (256,4) forced VGPR=64 -> catastrophic spills, 149MB scratch
// writes). Block = 2 waves splitting 64 N-cols; A panel 38 rows in LDS (19.5KB, 8
// blocks/CU = 157KB); barrier-free K-loop, B from L2 depth-4, A depth-2, cross-tap.

#define B_ 2
#define T_ 2048
#define L_ 4096
#define C_ 512

static constexpr int NUP = 512 * 512 * 4;
static constexpr int NR  = 512 * 512 * 7;

using v4i  = __attribute__((ext_vector_type(4))) int;
using v16i = __attribute__((ext_vector_type(16))) int;

__device__ __forceinline__ void gl16(const void* g, void* l) {
  __builtin_amdgcn_global_load_lds((const __attribute__((address_space(1))) unsigned int*)g,
                                   (__attribute__((address_space(3))) unsigned int*)l,
                                   16, 0, 0);
}

// ---------------- reductions ----------------

__device__ inline float block_reduce_sum_256(float v) {
  #pragma unroll
  for (int off = 32; off > 0; off >>= 1) v += __shfl_down(v, off, 64);
  __shared__ float s[4];
  __syncthreads();
  if ((threadIdx.x & 63) == 0) s[threadIdx.x >> 6] = v;
  __syncthreads();
  return (s[0] + s[1]) + (s[2] + s[3]);
}

// one launch: blockIdx.y selects tensor {0:w_up,1:w_r1,2:w_r2}
__global__ void abssum3_kernel(const float* __restrict__ w0, const float* __restrict__ w1,
                               const float* __restrict__ w2, float* __restrict__ out) {
  int y = blockIdx.y;
  const float* w = (y == 0) ? w0 : (y == 1) ? w1 : w2;
  int n = (y == 0) ? NUP : NR;
  int idx = blockIdx.x * 256 + threadIdx.x;
  float s = 0.f;
  for (int i = idx; i < n; i += gridDim.x * 256) s += fabsf(w[i]);
  s = block_reduce_sum_256(s);
  if (threadIdx.x == 0) atomicAdd(out + y, s);
}

// ---------------- ternarize + repack, one launch; layout [tap][kq32][co512][16] ----------------
__global__ void tern_all_kernel(const float* __restrict__ wu, const float* __restrict__ w1,
                                const float* __restrict__ w2, int8_t* __restrict__ ou,
                                int8_t* __restrict__ o1, int8_t* __restrict__ o2,
                                const float* __restrict__ wsum) {
  int y = blockIdx.y;
  int idx = blockIdx.x * 256 + threadIdx.x;
  if (y == 0) {
    if (idx >= NUP) return;
    float mean = wsum[0] * (1.0f / (float)NUP);
    float scale = 1.0f / fmaxf(mean, 1e-5f);
    float t = rintf(wu[idx] * scale);
    t = fminf(fmaxf(t, -1.f), 1.f);
    int ci = idx >> 11;
    int co = (idx >> 2) & 511;
    int k = idx & 3;
    // ptap order: parity0 {k=3,k=1}, parity1 {k=2,k=0}
    int ptap = (k == 3) ? 0 : (k == 1) ? 1 : (k == 2) ? 2 : 3;
    ou[(((size_t)ptap * 32 + (ci >> 4)) * 512 + co) * 16 + (ci & 15)] = (int8_t)t;
  } else {
    if (idx >= NR) return;
    const float* w = (y == 1) ? w1 : w2;
    int8_t* o = (y == 1) ? o1 : o2;
    float mean = wsum[y] * (1.0f / (float)NR);
    float scale = 1.0f / fmaxf(mean, 1e-5f);
    float t = rintf(w[idx] * scale);
    t = fminf(fmaxf(t, -1.f), 1.f);
    int co = idx / 3584;
    int rem = idx - co * 3584;
    int ci = rem / 7;
    int k = rem - ci * 7;
    o[(((size_t)k * 32 + (ci >> 4)) * 512 + co) * 16 + (ci & 15)] = (int8_t)t;
  }
}

// ---------------- per-token activation quant; packed q layout [b][kq32][LinH][16] ----------------
__global__ void act_quant_kernel(const float* __restrict__ x, int8_t* __restrict__ qd,
                                 float* __restrict__ inv, int Lb, int lbsh, int LinH) {
  int tok = blockIdx.x;
  int b = tok >> lbsh;
  int t = tok & (Lb - 1);
  const float* row = x + (size_t)tok * C_;
  int tid = threadIdx.x;
  float v0 = row[tid];
  float v1 = row[tid + 256];
  float m = fmaxf(fabsf(v0), fabsf(v1));
  #pragma unroll
  for (int off = 32; off > 0; off >>= 1) m = fmaxf(m, __shfl_down(m, off, 64));
  __shared__ float s[4];
  __shared__ __align__(16) int8_t sq[512];
  if ((tid & 63) == 0) s[tid >> 6] = m;
  __syncthreads();
  m = fmaxf(fmaxf(s[0], s[1]), fmaxf(s[2], s[3]));
  float scale = 127.0f / fmaxf(m, 1e-5f);
  float q0 = fminf(fmaxf(rintf(v0 * scale), -128.f), 127.f);
  float q1 = fminf(fmaxf(rintf(v1 * scale), -128.f), 127.f);
  sq[tid] = (int8_t)q0;
  sq[tid + 256] = (int8_t)q1;
  __syncthreads();
  if (tid < 32)
    *(v4i*)(qd + ((size_t)(b * 32 + tid) * LinH + 8 + t) * 16) = *(const v4i*)(sq + tid * 16);
  if (tid == 0) inv[(size_t)b * LinH + 8 + t] = 1.0f / scale;
}

// ---------------- MFMA conv: barrier-free per-tap int8 GEMM, wave tile 32x32 ----------------
// Block 128 thr (2 waves), tile 32(M) x 64(N); wave w covers cols [32w, 32w+32).
// sA[kq32][row38][16] staged once (buf row r <-> token t0-3+r); ONE barrier; depth-4 B /
// depth-2 A rolling prefetch crossing tap boundaries.
template<int NTAPS, bool CONVT>
__global__ __launch_bounds__(128)
void conv_mfma(const int8_t* __restrict__ qin, const float* __restrict__ invp, int LinH,
               const int8_t* __restrict__ wq, const float* __restrict__ wsum, int widx,
               float wninv, const float* __restrict__ bias, const float* __restrict__ res,
               float* __restrict__ outp, int Lout, int do_silu) {
  __shared__ __align__(16) int8_t sA[32 * 38 * 16];  // 19456 B
  __shared__ float sInv[38];

  const int tid = threadIdx.x;
  const int w = tid >> 6, lane = tid & 63, q = lane >> 5, l31 = lane & 31;
  const int n0 = (blockIdx.x & 7) * 64;
  const int t0 = (blockIdx.x >> 3) * 32;
  const int b = blockIdx.y;
  int s0 = -3;
  const int8_t* wq_p = wq;
  float* out_b = outp + (size_t)b * Lout * 512;
  int rstride = 512;
  if (CONVT) {
    int parity = blockIdx.z;
    s0 = parity - 1;
    wq_p += (size_t)parity * 2 * 32 * 512 * 16;
    out_b += parity * 512;
    rstride = 1024;
  }
  const int8_t* qin_b = qin + (size_t)b * 32 * LinH * 16;
  const float* inv_b = invp + (size_t)b * LinH + 8;

  // stage A once: 1216 units of 16B, [kq32][row38][16]; buf row r <-> token t0-3+r
  #pragma unroll
  for (int i = 0; i < 10; ++i) {
    int base = i * 128 + w * 64;
    if (base < 1216) {
      int u = base + lane;
      int kq = u / 38;
      int row = u - kq * 38;
      gl16(qin_b + ((size_t)kq * LinH + (size_t)(t0 + 5 + row)) * 16,
           sA + (size_t)base * 16);
    }
  }
  if (tid < 38) sInv[tid] = inv_b[t0 - 3 + tid];
  __syncthreads();  // the ONLY barrier

  float fs[16];
  #pragma unroll
  for (int r = 0; r < 16; ++r) fs[r] = 0.f;

  const int ncol = n0 + w * 32;

  // pipeline: A depth-2 (LDS), B depth-4 (global/L2)
  v4i afp[2], bfp[4];
  #pragma unroll
  for (int i = 0; i < 2; ++i) {
    int kq32 = i * 2 + q;
    afp[i] = *(const v4i*)(sA + ((size_t)kq32 * 38 + 3 + s0 + l31) * 16);
  }
  #pragma unroll
  for (int i = 0; i < 4; ++i) {
    int kq32 = i * 2 + q;
    bfp[i] = *(const v4i*)(wq_p + (((size_t)kq32 * 512) + ncol + l31) * 16);
  }

  for (int tap = 0; tap < NTAPS; ++tap) {
    const int shift = s0 + tap;
    v16i acc{};
    #pragma unroll
    for (int r = 0; r < 16; ++r) acc[r] = 0;
    #pragma unroll
    for (int ks = 0; ks < 16; ++ks) {
      v4i a_c = afp[ks & 1], b_c = bfp[ks & 3];
      // A prefetch (target step ks+2)
      if (ks < 14) {
        int kq32 = (ks + 2) * 2 + q;
        afp[ks & 1] = *(const v4i*)(sA + ((size_t)kq32 * 38 + 3 + shift + l31) * 16);
      } else if (tap + 1 < NTAPS) {
        int kq32 = (ks - 14) * 2 + q;
        afp[ks & 1] = *(const v4i*)(sA + ((size_t)kq32 * 38 + 3 + shift + 1 + l31) * 16);
      }
      // B prefetch (target step ks+4)
      if (ks < 12) {
        int kq32 = (ks + 4) * 2 + q;
        bfp[ks & 3] = *(const v4i*)(wq_p + (((size_t)(tap * 32 + kq32) * 512) + ncol + l31) * 16);
      } else if (tap + 1 < NTAPS) {
        int kq32 = (ks - 12) * 2 + q;
        bfp[ks & 3] = *(const v4i*)(wq_p + (((size_t)((tap + 1) * 32 + kq32) * 512) + ncol + l31) * 16);
      }
      acc = __builtin_amdgcn_mfma_i32_32x32x32_i8(a_c, b_c, acc, 0, 0, 0);
    }
    // fold i32 -> fp32 with per-input-row scale
    #pragma unroll
    for (int r = 0; r < 16; ++r) {
      int ro = (r & 3) + 8 * (r >> 2) + 4 * q;
      fs[r] = fmaf((float)acc[r], sInv[3 + shift + ro], fs[r]);
    }
  }

  float wdq = fmaxf(wsum[widx] * wninv, 1e-5f);
  int col = ncol + l31;
  float bv = bias[col];
  #pragma unroll
  for (int r = 0; r < 16; ++r) {
    int row = t0 + (r & 3) + 8 * (r >> 2) + 4 * q;
    float y = fs[r] * wdq + bv;
    if (do_silu) y = y / (1.0f + expf(-y));
    if (res) y += res[((size_t)b * Lout + row) * 512 + col];
    out_b[(size_t)row * rstride + col] = y;
  }
}

// ---------------- LayerNorm over channels ----------------
__global__ void ln_kernel(const float* __restrict__ x, const float* __restrict__ g,
                          const float* __restrict__ be, float* __restrict__ out) {
  int tok = blockIdx.x;
  const float* row = x + (size_t)tok * C_;
  int tid = threadIdx.x;
  float v0 = row[tid];
  float v1 = row[tid + 256];
  float total = block_reduce_sum_256(v0 + v1);
  float mu = total * (1.0f / (float)C_);
  float d0 = v0 - mu, d1 = v1 - mu;
  float vs = block_reduce_sum_256(d0 * d0 + d1 * d1);
  float var = vs * (1.0f / (float)C_);
  float r = 1.0f / sqrtf(var + 1e-5f);
  size_t base = (size_t)tok * C_;
  out[base + tid] = d0 * r * g[tid] + be[tid];
  out[base + tid + 256] = d1 * r * g[tid + 256] + be[tid + 256];
}

// ---------------- launch ----------------

extern "C" void kernel_launch(void* const* d_in, const int* in_sizes, int n_in,
                              void* d_out, int out_size, void* d_ws, size_t ws_size,
                              hipStream_t stream) {
  const float* x    = (const float*)d_in[0];
  const float* w_up = (const float*)d_in[1];
  const float* b_up = (const float*)d_in[2];
  const float* w_r1 = (const float*)d_in[3];
  const float* b_r1 = (const float*)d_in[4];
  const float* w_r2 = (const float*)d_in[5];
  const float* b_r2 = (const float*)d_in[6];
  const float* ln_w = (const float*)d_in[7];
  const float* ln_b = (const float*)d_in[8];
  float* out = (float*)d_out;

  const int LXH = T_ + 16;   // 2064 rows per batch (halo 8 each side)
  const int LHH = L_ + 16;   // 4112

  char* ws = (char*)d_ws;
  size_t off = 0;
  auto alloc = [&](size_t sz) { size_t p = off; off += (sz + 255) & ~(size_t)255; return p; };
  // wsum, qx, qh contiguous -> one zeroing memset
  float*  wsum = (float*) (ws + alloc(256));
  int8_t* qx   = (int8_t*)(ws + alloc((size_t)B_ * 32 * LXH * 16));   // 2.1 MB
  int8_t* qh   = (int8_t*)(ws + alloc((size_t)B_ * 32 * LHH * 16));   // 4.2 MB
  size_t zero_bytes = off;
  float*  invx = (float*) (ws + alloc((size_t)B_ * LXH * 4));
  float*  invh = (float*) (ws + alloc((size_t)B_ * LHH * 4));
  int8_t* wqup = (int8_t*)(ws + alloc((size_t)4 * 32 * 512 * 16));    // 1 MB
  int8_t* wq1  = (int8_t*)(ws + alloc((size_t)7 * 32 * 512 * 16));    // 1.8 MB
  int8_t* wq2  = (int8_t*)(ws + alloc((size_t)7 * 32 * 512 * 16));    // 1.8 MB
  float*  h    = (float*) (ws + alloc((size_t)B_ * L_ * C_ * 4));     // 16.8 MB
  float*  r    = (float*) (ws + alloc((size_t)B_ * L_ * C_ * 4));     // 16.8 MB

  hipMemsetAsync(ws, 0, zero_bytes, stream);  // wsum + qx + qh (zero halos)

  abssum3_kernel<<<dim3(256, 3), 256, 0, stream>>>(w_up, w_r1, w_r2, wsum);
  tern_all_kernel<<<dim3(NR / 256, 3), 256, 0, stream>>>(w_up, w_r1, w_r2,
                                                         wqup, wq1, wq2, wsum);

  act_quant_kernel<<<B_ * T_, 256, 0, stream>>>(x, qx, invx, T_, 11, LXH);

  // convT: grid (8 ntiles * 64 mtiles, B, parity); block tile 32M x 64N
  conv_mfma<2, true><<<dim3(8 * 64, B_, 2), 128, 0, stream>>>(
      qx, invx, LXH, wqup, wsum, 0, 1.0f / (float)NUP, b_up, nullptr, h, L_, 0);

  act_quant_kernel<<<B_ * L_, 256, 0, stream>>>(h, qh, invh, L_, 12, LHH);

  // conv7: grid (8 ntiles * 128 mtiles, B)
  conv_mfma<7, false><<<dim3(8 * 128, B_, 1), 128, 0, stream>>>(
      qh, invh, LHH, wq1, wsum, 1, 1.0f / (float)NR, b_r1, nullptr, r, L_, 1);

  act_quant_kernel<<<B_ * L_, 256, 0, stream>>>(r, qh, invh, L_, 12, LHH);

  conv_mfma<7, false><<<dim3(8 * 128, B_, 1), 128, 0, stream>>>(
      qh, invh, LHH, wq2, wsum, 2, 1.0f / (float)NR, b_r2, h, r, L_, 0);

  ln_kernel<<<B_ * L_, 256, 0, stream>>>(r, ln_w, ln_b, out);
}

// Round 10
// 216.657 us; speedup vs baseline: 1.5265x; 1.0746x over previous
//
#include <hip/hip_runtime.h>
#include <hip/hip_bf16.h>
#include <cstdint>
#include <cstddef>

// LearnableUpsampler: quant -> convT(K=4,s=2) -> quant -> conv7+silu -> quant -> conv7 + res -> LN
// Round 10: m97-style barriered K-loop (the HW-proven shape: 874 TF bf16 GEMM).
// Block 256 thr (4 waves), tile 64M x 128N, wave tile 32x64 (2 accs). A staged ONCE
// (70 rows x K=512, 35 KB, shared by all taps); B double-buffered per (tap,kc) K=128
// chunk (16 KB x2) via global_load_lds; 32 MFMA per barrier; prefetch issued before the
// burst so the barrier vmcnt drain is covered. 2 blocks/CU (LDS 68.9 KB) = 8 waves/CU.

#define B_ 2
#define T_ 2048
#define L_ 4096
#define C_ 512

static constexpr int NUP = 512 * 512 * 4;
static constexpr int NR  = 512 * 512 * 7;

using v4i  = __attribute__((ext_vector_type(4))) int;
using v16i = __attribute__((ext_vector_type(16))) int;

__device__ __forceinline__ void gl16(const void* g, void* l) {
  __builtin_amdgcn_global_load_lds((const __attribute__((address_space(1))) unsigned int*)g,
                                   (__attribute__((address_space(3))) unsigned int*)l,
                                   16, 0, 0);
}

// ---------------- reductions ----------------

__device__ inline float block_reduce_sum_256(float v) {
  #pragma unroll
  for (int off = 32; off > 0; off >>= 1) v += __shfl_down(v, off, 64);
  __shared__ float s[4];
  __syncthreads();
  if ((threadIdx.x & 63) == 0) s[threadIdx.x >> 6] = v;
  __syncthreads();
  return (s[0] + s[1]) + (s[2] + s[3]);
}

// one launch: blockIdx.y selects tensor {0:w_up,1:w_r1,2:w_r2}
__global__ void abssum3_kernel(const float* __restrict__ w0, const float* __restrict__ w1,
                               const float* __restrict__ w2, float* __restrict__ out) {
  int y = blockIdx.y;
  const float* w = (y == 0) ? w0 : (y == 1) ? w1 : w2;
  int n = (y == 0) ? NUP : NR;
  int idx = blockIdx.x * 256 + threadIdx.x;
  float s = 0.f;
  for (int i = idx; i < n; i += gridDim.x * 256) s += fabsf(w[i]);
  s = block_reduce_sum_256(s);
  if (threadIdx.x == 0) atomicAdd(out + y, s);
}

// ---------------- ternarize + repack, one launch; layout [tap][kq32][co512][16] ----------------
__global__ void tern_all_kernel(const float* __restrict__ wu, const float* __restrict__ w1,
                                const float* __restrict__ w2, int8_t* __restrict__ ou,
                                int8_t* __restrict__ o1, int8_t* __restrict__ o2,
                                const float* __restrict__ wsum) {
  int y = blockIdx.y;
  int idx = blockIdx.x * 256 + threadIdx.x;
  if (y == 0) {
    if (idx >= NUP) return;
    float mean = wsum[0] * (1.0f / (float)NUP);
    float scale = 1.0f / fmaxf(mean, 1e-5f);
    float t = rintf(wu[idx] * scale);
    t = fminf(fmaxf(t, -1.f), 1.f);
    int ci = idx >> 11;
    int co = (idx >> 2) & 511;
    int k = idx & 3;
    // ptap order: parity0 {k=3,k=1}, parity1 {k=2,k=0}
    int ptap = (k == 3) ? 0 : (k == 1) ? 1 : (k == 2) ? 2 : 3;
    ou[(((size_t)ptap * 32 + (ci >> 4)) * 512 + co) * 16 + (ci & 15)] = (int8_t)t;
  } else {
    if (idx >= NR) return;
    const float* w = (y == 1) ? w1 : w2;
    int8_t* o = (y == 1) ? o1 : o2;
    float mean = wsum[y] * (1.0f / (float)NR);
    float scale = 1.0f / fmaxf(mean, 1e-5f);
    float t = rintf(w[idx] * scale);
    t = fminf(fmaxf(t, -1.f), 1.f);
    int co = idx / 3584;
    int rem = idx - co * 3584;
    int ci = rem / 7;
    int k = rem - ci * 7;
    o[(((size_t)k * 32 + (ci >> 4)) * 512 + co) * 16 + (ci & 15)] = (int8_t)t;
  }
}

// ---------------- per-token activation quant; packed q layout [b][kq32][LinH][16] ----------------
__global__ void act_quant_kernel(const float* __restrict__ x, int8_t* __restrict__ qd,
                                 float* __restrict__ inv, int Lb, int lbsh, int LinH) {
  int tok = blockIdx.x;
  int b = tok >> lbsh;
  int t = tok & (Lb - 1);
  const float* row = x + (size_t)tok * C_;
  int tid = threadIdx.x;
  float v0 = row[tid];
  float v1 = row[tid + 256];
  float m = fmaxf(fabsf(v0), fabsf(v1));
  #pragma unroll
  for (int off = 32; off > 0; off >>= 1) m = fmaxf(m, __shfl_down(m, off, 64));
  __shared__ float s[4];
  __shared__ __align__(16) int8_t sq[512];
  if ((tid & 63) == 0) s[tid >> 6] = m;
  __syncthreads();
  m = fmaxf(fmaxf(s[0], s[1]), fmaxf(s[2], s[3]));
  float scale = 127.0f / fmaxf(m, 1e-5f);
  float q0 = fminf(fmaxf(rintf(v0 * scale), -128.f), 127.f);
  float q1 = fminf(fmaxf(rintf(v1 * scale), -128.f), 127.f);
  sq[tid] = (int8_t)q0;
  sq[tid + 256] = (int8_t)q1;
  __syncthreads();
  if (tid < 32)
    *(v4i*)(qd + ((size_t)(b * 32 + tid) * LinH + 8 + t) * 16) = *(const v4i*)(sq + tid * 16);
  if (tid == 0) inv[(size_t)b * LinH + 8 + t] = 1.0f / scale;
}

// ---------------- MFMA conv: barriered double-buffered-B int8 GEMM (m97 shape) ----------------
// Block 256 thr (4 waves): wave w -> (mh = w&1, nh = w>>1); wave tile 32(M) x 64(N).
// sA[kq32][row70][16] staged once (token t0-3+row); sB[2][kq8][co128][16] per K=128 chunk.
// 28 chunks (tap x kc); per chunk: prefetch next B, 8 MFMA/wave (32/block), barrier.
template<int NTAPS, bool CONVT>
__global__ __launch_bounds__(256)
void conv_mfma(const int8_t* __restrict__ qin, const float* __restrict__ invp, int LinH,
               const int8_t* __restrict__ wq, const float* __restrict__ wsum, int widx,
               float wninv, const float* __restrict__ bias, const float* __restrict__ res,
               float* __restrict__ outp, int Lout, int do_silu) {
  __shared__ __align__(16) int8_t sA[32 * 70 * 16];      // 35840 B
  __shared__ __align__(16) int8_t sB[2][8 * 128 * 16];   // 2 x 16384 B
  __shared__ float sInv[72];

  const int tid = threadIdx.x;
  const int w = tid >> 6, lane = tid & 63, q = lane >> 5, l31 = lane & 31;
  const int mh = w & 1, nh = w >> 1;
  const int n0 = (blockIdx.x & 3) * 128;
  const int t0 = (blockIdx.x >> 2) * 64;
  const int b = blockIdx.y;
  int s0 = -3;
  const int8_t* wq_p = wq;
  float* out_b = outp + (size_t)b * Lout * 512;
  int rstride = 512;
  if (CONVT) {
    int parity = blockIdx.z;
    s0 = parity - 1;
    wq_p += (size_t)parity * 2 * 32 * 512 * 16;
    out_b += parity * 512;
    rstride = 1024;
  }
  const int8_t* qin_b = qin + (size_t)b * 32 * LinH * 16;
  const float* inv_b = invp + (size_t)b * LinH + 8;

  // ---- B chunk staging: chunk j = (tap, kc); 1024 16B units -> sB[buf]
  auto stageB = [&](int j, int buf) {
    int tap = j >> 2, kc = j & 3;
    const int8_t* wt = wq_p + ((size_t)(tap * 32 + kc * 8) * 512 + n0) * 16;
    #pragma unroll
    for (int i = 0; i < 4; ++i) {
      int u = i * 256 + tid;
      gl16(wt + ((size_t)(u >> 7) * 512 + (u & 127)) * 16,
           sB[buf] + (size_t)(i * 256 + w * 64) * 16);
    }
  };

  // stage first B chunk, then A (2240 units), then scales
  stageB(0, 0);
  #pragma unroll
  for (int i = 0; i < 9; ++i) {
    int base = i * 256 + w * 64;       // wave-uniform
    if (base < 2240) {
      int u = base + lane;
      int kq = u / 70;
      int row = u - kq * 70;
      gl16(qin_b + ((size_t)kq * LinH + (size_t)(t0 + 5 + row)) * 16,
           sA + (size_t)base * 16);
    }
  }
  if (tid < 70) sInv[tid] = inv_b[t0 - 3 + tid];
  __syncthreads();

  float fs0[16], fs1[16];
  v16i acc0{}, acc1{};
  #pragma unroll
  for (int r = 0; r < 16; ++r) { fs0[r] = 0.f; fs1[r] = 0.f; acc0[r] = 0; acc1[r] = 0; }

  constexpr int NCH = NTAPS * 4;

  auto doChunk = [&](int j, int cur) {
    const int tap = j >> 2, kc = j & 3;
    const int shift = s0 + tap;
    if (j + 1 < NCH) stageB(j + 1, cur ^ 1);   // prefetch before the MFMA burst
    const int arow = 3 + shift + mh * 32 + l31;
    #pragma unroll
    for (int s = 0; s < 4; ++s) {
      int kqc = s * 2 + q;
      v4i a  = *(const v4i*)(sA + ((size_t)((kc * 8 + kqc) * 70) + arow) * 16);
      v4i b0 = *(const v4i*)(sB[cur] + ((size_t)kqc * 128 + nh * 64 + l31) * 16);
      v4i b1 = *(const v4i*)(sB[cur] + ((size_t)kqc * 128 + nh * 64 + 32 + l31) * 16);
      acc0 = __builtin_amdgcn_mfma_i32_32x32x32_i8(a, b0, acc0, 0, 0, 0);
      acc1 = __builtin_amdgcn_mfma_i32_32x32x32_i8(a, b1, acc1, 0, 0, 0);
    }
    if (kc == 3) {  // end of tap: fold i32 -> fp32 with per-input-row scale
      #pragma unroll
      for (int r = 0; r < 16; ++r) {
        int ro = (r & 3) + 8 * (r >> 2) + 4 * q;
        float sc = sInv[3 + shift + mh * 32 + ro];
        fs0[r] = fmaf((float)acc0[r], sc, fs0[r]);
        fs1[r] = fmaf((float)acc1[r], sc, fs1[r]);
        acc0[r] = 0;
        acc1[r] = 0;
      }
    }
    __syncthreads();
  };

  #pragma unroll 1
  for (int j = 0; j < NCH; j += 2) {
    doChunk(j, 0);
    doChunk(j + 1, 1);
  }

  float wdq = fmaxf(wsum[widx] * wninv, 1e-5f);
  #pragma unroll
  for (int nt = 0; nt < 2; ++nt) {
    int col = n0 + nh * 64 + nt * 32 + l31;
    float bv = bias[col];
    #pragma unroll
    for (int r = 0; r < 16; ++r) {
      int row = t0 + mh * 32 + (r & 3) + 8 * (r >> 2) + 4 * q;
      float y = (nt == 0 ? fs0[r] : fs1[r]) * wdq + bv;
      if (do_silu) y = y / (1.0f + expf(-y));
      if (res) y += res[((size_t)b * Lout + row) * 512 + col];
      out_b[(size_t)row * rstride + col] = y;
    }
  }
}

// ---------------- LayerNorm over channels ----------------
__global__ void ln_kernel(const float* __restrict__ x, const float* __restrict__ g,
                          const float* __restrict__ be, float* __restrict__ out) {
  int tok = blockIdx.x;
  const float* row = x + (size_t)tok * C_;
  int tid = threadIdx.x;
  float v0 = row[tid];
  float v1 = row[tid + 256];
  float total = block_reduce_sum_256(v0 + v1);
  float mu = total * (1.0f / (float)C_);
  float d0 = v0 - mu, d1 = v1 - mu;
  float vs = block_reduce_sum_256(d0 * d0 + d1 * d1);
  float var = vs * (1.0f / (float)C_);
  float r = 1.0f / sqrtf(var + 1e-5f);
  size_t base = (size_t)tok * C_;
  out[base + tid] = d0 * r * g[tid] + be[tid];
  out[base + tid + 256] = d1 * r * g[tid + 256] + be[tid + 256];
}

// ---------------- launch ----------------

extern "C" void kernel_launch(void* const* d_in, const int* in_sizes, int n_in,
                              void* d_out, int out_size, void* d_ws, size_t ws_size,
                              hipStream_t stream) {
  const float* x    = (const float*)d_in[0];
  const float* w_up = (const float*)d_in[1];
  const float* b_up = (const float*)d_in[2];
  const float* w_r1 = (const float*)d_in[3];
  const float* b_r1 = (const float*)d_in[4];
  const float* w_r2 = (const float*)d_in[5];
  const float* b_r2 = (const float*)d_in[6];
  const float* ln_w = (const float*)d_in[7];
  const float* ln_b = (const float*)d_in[8];
  float* out = (float*)d_out;

  const int LXH = T_ + 16;   // 2064 rows per batch (halo 8 each side)
  const int LHH = L_ + 16;   // 4112

  char* ws = (char*)d_ws;
  size_t off = 0;
  auto alloc = [&](size_t sz) { size_t p = off; off += (sz + 255) & ~(size_t)255; return p; };
  // wsum, qx, qh contiguous -> one zeroing memset
  float*  wsum = (float*) (ws + alloc(256));
  int8_t* qx   = (int8_t*)(ws + alloc((size_t)B_ * 32 * LXH * 16));   // 2.1 MB
  int8_t* qh   = (int8_t*)(ws + alloc((size_t)B_ * 32 * LHH * 16));   // 4.2 MB
  size_t zero_bytes = off;
  float*  invx = (float*) (ws + alloc((size_t)B_ * LXH * 4));
  float*  invh = (float*) (ws + alloc((size_t)B_ * LHH * 4));
  int8_t* wqup = (int8_t*)(ws + alloc((size_t)4 * 32 * 512 * 16));    // 1 MB
  int8_t* wq1  = (int8_t*)(ws + alloc((size_t)7 * 32 * 512 * 16));    // 1.8 MB
  int8_t* wq2  = (int8_t*)(ws + alloc((size_t)7 * 32 * 512 * 16));    // 1.8 MB
  float*  h    = (float*) (ws + alloc((size_t)B_ * L_ * C_ * 4));     // 16.8 MB
  float*  r    = (float*) (ws + alloc((size_t)B_ * L_ * C_ * 4));     // 16.8 MB

  hipMemsetAsync(ws, 0, zero_bytes, stream);  // wsum + qx + qh (zero halos)

  abssum3_kernel<<<dim3(256, 3), 256, 0, stream>>>(w_up, w_r1, w_r2, wsum);
  tern_all_kernel<<<dim3(NR / 256, 3), 256, 0, stream>>>(w_up, w_r1, w_r2,
                                                         wqup, wq1, wq2, wsum);

  act_quant_kernel<<<B_ * T_, 256, 0, stream>>>(x, qx, invx, T_, 11, LXH);

  // convT: grid (4 ntiles * 32 mtiles, B, parity); block tile 64M x 128N
  conv_mfma<2, true><<<dim3(4 * 32, B_, 2), 256, 0, stream>>>(
      qx, invx, LXH, wqup, wsum, 0, 1.0f / (float)NUP, b_up, nullptr, h, L_, 0);

  act_quant_kernel<<<B_ * L_, 256, 0, stream>>>(h, qh, invh, L_, 12, LHH);

  // conv7: grid (4 ntiles * 64 mtiles, B) = 512 blocks = 2/CU exactly
  conv_mfma<7, false><<<dim3(4 * 64, B_, 1), 256, 0, stream>>>(
      qh, invh, LHH, wq1, wsum, 1, 1.0f / (float)NR, b_r1, nullptr, r, L_, 1);

  act_quant_kernel<<<B_ * L_, 256, 0, stream>>>(r, qh, invh, L_, 12, LHH);

  conv_mfma<7, false><<<dim3(4 * 64, B_, 1), 256, 0, stream>>>(
      qh, invh, LHH, wq2, wsum, 2, 1.0f / (float)NR, b_r2, h, r, L_, 0);

  ln_kernel<<<B_ * L_, 256, 0, stream>>>(r, ln_w, ln_b, out);
}